// Round 1
// baseline (373.111 us; speedup 1.0000x reference)
//
#include <hip/hip_runtime.h>
#include <hip/hip_bf16.h>

// B=8, T=4096 -> 32768 tokens, D=1024, V=64.
// R5 restructure:
//  - LDS 44.5KB -> 39.6KB (single sLogP via full-K Phase B) + launch_bounds(512,8)
//    => 4 blocks/CU (was 3), occupancy 62% -> ~80%.
//  - Phase C: margin-ballot candidate set (Delta=2.5) replaces serial top-4
//    extraction (24 dependent shuffles + 4 ballots -> 1 ballot, ~1.5 avg cands).
//  - Phase D: operand-swapped MFMA (D rows=dim, cols=token) -> packed
//    ds_write_b64 of soft_emb into reused sX1b; final blend from exact fp32
//    registers with float4 stores (was 32 scalar dword stores + bf16 x1).

#define DIMS 1024
#define VOCAB 64
#define NTOK 32768
#define TTILE 16
#define TPB 512
#define IDX_OFF (NTOK * DIMS)
#define CAND_DELTA 2.5f

typedef __attribute__((ext_vector_type(8))) short short8;   // 8 x bf16
typedef __attribute__((ext_vector_type(4))) float f32x4;

__device__ __forceinline__ float sigm(float z) {
    return 1.f / (1.f + __expf(-z));
}
__device__ __forceinline__ unsigned short f2bf(float f) {
    __hip_bfloat16 h = __float2bfloat16(f);   // RTNE
    return *reinterpret_cast<unsigned short*>(&h);
}
__device__ __forceinline__ float bf2f(unsigned short u) {
    __hip_bfloat16 h = *reinterpret_cast<__hip_bfloat16*>(&u);
    return __bfloat162float(h);
}

// headB[v][d]=bf16(head), embT[d][v]=bf16(emb^T). 128KB each in d_ws.
__global__ void prep_weights(const float* __restrict__ head,
                             const float* __restrict__ emb,
                             __hip_bfloat16* __restrict__ headB,
                             __hip_bfloat16* __restrict__ embT) {
    int t = blockIdx.x * 256 + threadIdx.x;   // v*1024+d
    int v = t >> 10, d = t & 1023;
    headB[t] = __float2bfloat16(head[t]);
    embT[d * VOCAB + v] = __float2bfloat16(emb[v * DIMS + d]);
}

__global__ __launch_bounds__(TPB, 8) void fused_block(
    const float* __restrict__ x,
    const int* __restrict__ idx,
    const float* __restrict__ emb,
    const float* __restrict__ gate,
    const float* __restrict__ sgate,
    const float* __restrict__ headF,          // fp32 head (exact recompute)
    const __hip_bfloat16* __restrict__ headB,
    const __hip_bfloat16* __restrict__ embT,
    float* __restrict__ out)
{
    // sX1b: x1 bf16 for Phase B MFMA; reused for soft_emb bf16 in Phase D.
    __shared__ __align__(16) __hip_bfloat16 sX1b[TTILE][1032];   // 33,024 B
    __shared__ __align__(16) float          sLogP[TTILE][66];    //  4,224 B
    __shared__ __align__(16) __hip_bfloat16 sP[TTILE][72];       //  2,304 B
    __shared__ float sSg[TTILE];                                 // total 39.6 KB -> 4 blk/CU

    const int tid  = threadIdx.x;
    const int tk   = tid >> 5;        // token-in-tile 0..15 (32 lanes each)
    const int l32  = tid & 31;
    const long t0  = (long)blockIdx.x * TTILE;
    const long tok = t0 + tk;

    // ---------- Phase A: load x, g-blend with emb[idx], sg; x1 -> regs(fp32) + LDS(bf16) ----------
    float4 xv[8];                     // x1 at d = 4*(l32 + c*32) .. +3
    float gsum = 0.f;
    const float4* xrow = (const float4*)(x + tok * DIMS);
    const float4* grow = (const float4*)gate;
    #pragma unroll
    for (int c = 0; c < 8; c++) {
        int f = l32 + c * 32;
        float4 v = xrow[f];
        float4 gv = grow[f];
        xv[c] = v;
        gsum += sigm(v.x * gv.x) + sigm(v.y * gv.y)
              + sigm(v.z * gv.z) + sigm(v.w * gv.w);
    }
    gsum += __shfl_xor(gsum, 1); gsum += __shfl_xor(gsum, 2);
    gsum += __shfl_xor(gsum, 4); gsum += __shfl_xor(gsum, 8);
    gsum += __shfl_xor(gsum, 16);
    const float g = gsum * (1.f / 1024.f);

    int ic = idx[tok]; if (ic < 0) ic = 0;            // jnp.clip(idx, 0, None)
    const float4* erow = (const float4*)(emb + (long)ic * DIMS);
    const float4* srow = (const float4*)sgate;
    float ssum = 0.f;
    #pragma unroll
    for (int c = 0; c < 8; c++) {
        int f = l32 + c * 32;
        float4 ev = erow[f];
        float4 sv = srow[f];
        float4 a;
        a.x = xv[c].x * (1.f - g) + ev.x * g;
        a.y = xv[c].y * (1.f - g) + ev.y * g;
        a.z = xv[c].z * (1.f - g) + ev.z * g;
        a.w = xv[c].w * (1.f - g) + ev.w * g;
        xv[c] = a;                                    // exact fp32 x1 stays in regs
        ssum += sigm(a.x * sv.x) + sigm(a.y * sv.y)
              + sigm(a.z * sv.z) + sigm(a.w * sv.w);
        ushort4 pk;
        pk.x = f2bf(a.x); pk.y = f2bf(a.y); pk.z = f2bf(a.z); pk.w = f2bf(a.w);
        *(ushort4*)&sX1b[tk][f * 4] = pk;
    }
    ssum += __shfl_xor(ssum, 1); ssum += __shfl_xor(ssum, 2);
    ssum += __shfl_xor(ssum, 4); ssum += __shfl_xor(ssum, 8);
    ssum += __shfl_xor(ssum, 16);
    if (l32 == 0) sSg[tk] = ssum * (1.f / 1024.f);
    __syncthreads();

    // ---------- Phase B: approx logits via bf16 MFMA, full-K, waves 0..3 own vocab tiles ----------
    const int w    = tid >> 6;        // wave 0..7
    const int lane = tid & 63;
    const int quad = lane >> 4, l16 = lane & 15;
    if (w < 4) {
        f32x4 acc0 = {0.f, 0.f, 0.f, 0.f};
        f32x4 acc1 = {0.f, 0.f, 0.f, 0.f};
        const __hip_bfloat16* hrow = headB + (long)(w * 16 + l16) * DIMS + quad * 8;
        #pragma unroll 2
        for (int k0 = 0; k0 < 1024; k0 += 64) {
            short8 a0 = *(const short8*)&sX1b[l16][k0 + quad * 8];
            short8 b0 = *(const short8*)(hrow + k0);
            acc0 = __builtin_amdgcn_mfma_f32_16x16x32_bf16(a0, b0, acc0, 0, 0, 0);
            short8 a1 = *(const short8*)&sX1b[l16][k0 + 32 + quad * 8];
            short8 b1 = *(const short8*)(hrow + k0 + 32);
            acc1 = __builtin_amdgcn_mfma_f32_16x16x32_bf16(a1, b1, acc1, 0, 0, 0);
        }
        #pragma unroll
        for (int i = 0; i < 4; i++)
            sLogP[quad * 4 + i][w * 16 + l16] = acc0[i] + acc1[i];  // D: row=quad*4+i, col=l16
    }
    __syncthreads();

    // ---------- Phase C: softmax + margin candidate mask (wave w owns tokens 2w, 2w+1) ----------
    unsigned long long candA, candB;
    {
        float lA = sLogP[2 * w][lane];
        float lB = sLogP[2 * w + 1][lane];
        float mA = lA, mB = lB;
        #pragma unroll
        for (int k = 1; k < 64; k <<= 1) {              // interleaved chains for ILP
            mA = fmaxf(mA, __shfl_xor(mA, k));
            mB = fmaxf(mB, __shfl_xor(mB, k));
        }
        float eA = __expf(lA - mA), eB = __expf(lB - mB);
        float sA = eA, sB = eB;
        #pragma unroll
        for (int k = 1; k < 64; k <<= 1) {
            sA += __shfl_xor(sA, k);
            sB += __shfl_xor(sB, k);
        }
        sP[2 * w][lane]     = __float2bfloat16(eA / sA);
        sP[2 * w + 1][lane] = __float2bfloat16(eB / sB);
        // True argmax has approx logit >= mx - 2*eps; Delta=2.5 ~ 15 sigma of
        // the bf16 logit error (sigma ~ 0.13) -- strictly safer than top-4.
        candA = __ballot(lA >= mA - CAND_DELTA);
        candB = __ballot(lB >= mB - CAND_DELTA);
    }

    // ---------- Phase C'': exact fp32 logits for candidates; argmax (half-wave per token) ----------
    {
        unsigned long long cm = ((lane >> 5) & 1) ? candB : candA;
        float bv = -3.4e38f; int bi = 0;
        while (cm) {                                    // ascending v -> ties keep lowest idx
            int v = __ffsll(cm) - 1;
            cm &= cm - 1;
            const float4* hr = (const float4*)(headF + (long)v * DIMS);
            float p = 0.f;
            #pragma unroll
            for (int c = 0; c < 8; c++) {
                float4 hv = hr[l32 + c * 32];
                p = fmaf(xv[c].x, hv.x, p); p = fmaf(xv[c].y, hv.y, p);
                p = fmaf(xv[c].z, hv.z, p); p = fmaf(xv[c].w, hv.w, p);
            }
            p += __shfl_xor(p, 1); p += __shfl_xor(p, 2);
            p += __shfl_xor(p, 4); p += __shfl_xor(p, 8);
            p += __shfl_xor(p, 16);                     // reduce within 32-lane half
            if (p > bv) { bv = p; bi = v; }
        }
        if (l32 == 0) out[IDX_OFF + tok] = (float)bi;   // tok == t0 + (tid>>5) == 2w+h token
    }
    __syncthreads();   // sP writes (C) visible before D reads; sX1b reads (B) done before D writes

    // ---------- Phase D: soft_emb = (embT-tile).P via swapped-operand MFMA ----------
    // A = embT tile (rows = dim n), B = P (cols = token) => D: row = n-in-tile, col = token.
    // Lane holds 4 consecutive dims of ONE token -> packed ds_write_b64 into sX1b.
    {
        short8 pb0 = *(const short8*)&sP[l16][quad * 8];        // loop-invariant
        short8 pb1 = *(const short8*)&sP[l16][32 + quad * 8];
        #pragma unroll 2
        for (int i = 0; i < 8; i++) {
            int n0 = (i * 8 + w) * 16;                  // 64 wave-disjoint n-tiles
            const __hip_bfloat16* er = embT + (long)(n0 + l16) * VOCAB + quad * 8;
            f32x4 acc = {0.f, 0.f, 0.f, 0.f};
            acc = __builtin_amdgcn_mfma_f32_16x16x32_bf16(*(const short8*)er, pb0, acc, 0, 0, 0);
            acc = __builtin_amdgcn_mfma_f32_16x16x32_bf16(*(const short8*)(er + 32), pb1, acc, 0, 0, 0);
            ushort4 pk;
            pk.x = f2bf(acc[0]); pk.y = f2bf(acc[1]);
            pk.z = f2bf(acc[2]); pk.w = f2bf(acc[3]);
            *(ushort4*)&sX1b[l16][n0 + quad * 4] = pk;  // token=l16, dims n0+quad*4..+3
        }
    }
    __syncthreads();

    // ---------- Final blend: exact fp32 x1 (regs) + bf16 soft_emb (LDS) -> float4 stores ----------
    {
        const float sg = sSg[tk];
        float4* orow = (float4*)(out + tok * DIMS);
        #pragma unroll
        for (int c = 0; c < 8; c++) {
            int f = l32 + c * 32;
            ushort4 se = *(const ushort4*)&sX1b[tk][f * 4];
            float4 o;
            o.x = xv[c].x * (1.f - sg) + bf2f(se.x) * sg;
            o.y = xv[c].y * (1.f - sg) + bf2f(se.y) * sg;
            o.z = xv[c].z * (1.f - sg) + bf2f(se.z) * sg;
            o.w = xv[c].w * (1.f - sg) + bf2f(se.w) * sg;
            orow[f] = o;
        }
    }
}

extern "C" void kernel_launch(void* const* d_in, const int* in_sizes, int n_in,
                              void* d_out, int out_size, void* d_ws, size_t ws_size,
                              hipStream_t stream) {
    const float* xp    = (const float*)d_in[0];
    const int*   idxp  = (const int*)d_in[1];
    const float* embp  = (const float*)d_in[2];
    const float* headp = (const float*)d_in[3];
    const float* gp    = (const float*)d_in[4];
    const float* sgp   = (const float*)d_in[5];
    float*       outp  = (float*)d_out;

    __hip_bfloat16* headB = (__hip_bfloat16*)d_ws;                        // 128 KB
    __hip_bfloat16* embT  = (__hip_bfloat16*)((char*)d_ws + 131072);      // 128 KB

    prep_weights<<<dim3(256), dim3(256), 0, stream>>>(headp, embp, headB, embT);
    fused_block<<<dim3(NTOK / TTILE), dim3(TPB), 0, stream>>>(
        xp, idxp, embp, gp, sgp, headp, headB, embT, outp);
}

// Round 2
// 356.812 us; speedup vs baseline: 1.0457x; 1.0457x over previous
//
#include <hip/hip_runtime.h>
#include <hip/hip_bf16.h>

// B=8, T=4096 -> 32768 tokens, D=1024, V=64.
// R6 = R4 memory behavior + R5 occupancy wins, minus R5's register spill:
//  - LDS 39.6KB (single sLogP, full-K Phase B) + launch_bounds(512,8) -> 4 blk/CU.
//  - Margin-ballot candidate set (Delta=2.5) for exact argmax (1 ballot vs
//    serial top-4 extraction).
//  - xv[8] (exact fp32 x1) live only through Phase C'' -- R5 kept it to the
//    last store under a 64-VGPR budget and spilled (VGPR_Count=32, +400MB HBM).
//  - Phase D: R4-proven un-swapped MFMA; blend reads bf16 x1 from sX1b
//    (absmax unchanged vs exact fp32: 0.156 vs 0.158) and stores direct to out.

#define DIMS 1024
#define VOCAB 64
#define NTOK 32768
#define TTILE 16
#define TPB 512
#define IDX_OFF (NTOK * DIMS)
#define CAND_DELTA 2.5f

typedef __attribute__((ext_vector_type(8))) short short8;   // 8 x bf16
typedef __attribute__((ext_vector_type(4))) float f32x4;

__device__ __forceinline__ float sigm(float z) {
    return 1.f / (1.f + __expf(-z));
}
__device__ __forceinline__ unsigned short f2bf(float f) {
    __hip_bfloat16 h = __float2bfloat16(f);   // RTNE
    return *reinterpret_cast<unsigned short*>(&h);
}
__device__ __forceinline__ float bf2f(unsigned short u) {
    __hip_bfloat16 h = *reinterpret_cast<__hip_bfloat16*>(&u);
    return __bfloat162float(h);
}

// headB[v][d]=bf16(head), embT[d][v]=bf16(emb^T). 128KB each in d_ws.
__global__ void prep_weights(const float* __restrict__ head,
                             const float* __restrict__ emb,
                             __hip_bfloat16* __restrict__ headB,
                             __hip_bfloat16* __restrict__ embT) {
    int t = blockIdx.x * 256 + threadIdx.x;   // v*1024+d
    int v = t >> 10, d = t & 1023;
    headB[t] = __float2bfloat16(head[t]);
    embT[d * VOCAB + v] = __float2bfloat16(emb[v * DIMS + d]);
}

__global__ __launch_bounds__(TPB, 8) void fused_block(
    const float* __restrict__ x,
    const int* __restrict__ idx,
    const float* __restrict__ emb,
    const float* __restrict__ gate,
    const float* __restrict__ sgate,
    const float* __restrict__ headF,          // fp32 head (exact recompute)
    const __hip_bfloat16* __restrict__ headB,
    const __hip_bfloat16* __restrict__ embT,
    float* __restrict__ out)
{
    __shared__ __align__(16) __hip_bfloat16 sX1b[TTILE][1032];   // 33,024 B
    __shared__ __align__(16) float          sLogP[TTILE][66];    //  4,224 B
    __shared__ __align__(16) __hip_bfloat16 sP[TTILE][72];       //  2,304 B
    __shared__ float sSg[TTILE];                                 // total 39.6 KB -> 4 blk/CU

    const int tid  = threadIdx.x;
    const int tk   = tid >> 5;        // token-in-tile 0..15 (32 lanes each)
    const int l32  = tid & 31;
    const long t0  = (long)blockIdx.x * TTILE;
    const long tok = t0 + tk;

    // ---------- Phase A: load x, g-blend with emb[idx], sg; x1 -> regs(fp32) + LDS(bf16) ----------
    float4 xv[8];                     // x1 at d = 4*(l32 + c*32) .. +3; dies at Phase C''
    float gsum = 0.f;
    const float4* xrow = (const float4*)(x + tok * DIMS);
    const float4* grow = (const float4*)gate;
    #pragma unroll
    for (int c = 0; c < 8; c++) {
        int f = l32 + c * 32;
        float4 v = xrow[f];
        float4 gv = grow[f];
        xv[c] = v;
        gsum += sigm(v.x * gv.x) + sigm(v.y * gv.y)
              + sigm(v.z * gv.z) + sigm(v.w * gv.w);
    }
    gsum += __shfl_xor(gsum, 1); gsum += __shfl_xor(gsum, 2);
    gsum += __shfl_xor(gsum, 4); gsum += __shfl_xor(gsum, 8);
    gsum += __shfl_xor(gsum, 16);
    const float g = gsum * (1.f / 1024.f);

    int ic = idx[tok]; if (ic < 0) ic = 0;            // jnp.clip(idx, 0, None)
    const float4* erow = (const float4*)(emb + (long)ic * DIMS);
    const float4* srow = (const float4*)sgate;
    float ssum = 0.f;
    #pragma unroll
    for (int c = 0; c < 8; c++) {
        int f = l32 + c * 32;
        float4 ev = erow[f];
        float4 sv = srow[f];
        float4 a;
        a.x = xv[c].x * (1.f - g) + ev.x * g;
        a.y = xv[c].y * (1.f - g) + ev.y * g;
        a.z = xv[c].z * (1.f - g) + ev.z * g;
        a.w = xv[c].w * (1.f - g) + ev.w * g;
        xv[c] = a;                                    // exact fp32 x1 (for argmax recompute)
        ssum += sigm(a.x * sv.x) + sigm(a.y * sv.y)
              + sigm(a.z * sv.z) + sigm(a.w * sv.w);
        ushort4 pk;
        pk.x = f2bf(a.x); pk.y = f2bf(a.y); pk.z = f2bf(a.z); pk.w = f2bf(a.w);
        *(ushort4*)&sX1b[tk][f * 4] = pk;
    }
    ssum += __shfl_xor(ssum, 1); ssum += __shfl_xor(ssum, 2);
    ssum += __shfl_xor(ssum, 4); ssum += __shfl_xor(ssum, 8);
    ssum += __shfl_xor(ssum, 16);
    if (l32 == 0) sSg[tk] = ssum * (1.f / 1024.f);
    __syncthreads();

    // ---------- Phase B: approx logits via bf16 MFMA, full-K, waves 0..3 own vocab tiles ----------
    const int w    = tid >> 6;        // wave 0..7
    const int lane = tid & 63;
    const int quad = lane >> 4, l16 = lane & 15;
    if (w < 4) {
        f32x4 acc0 = {0.f, 0.f, 0.f, 0.f};
        f32x4 acc1 = {0.f, 0.f, 0.f, 0.f};
        const __hip_bfloat16* hrow = headB + (long)(w * 16 + l16) * DIMS + quad * 8;
        #pragma unroll 2
        for (int k0 = 0; k0 < 1024; k0 += 64) {
            short8 a0 = *(const short8*)&sX1b[l16][k0 + quad * 8];
            short8 b0 = *(const short8*)(hrow + k0);
            acc0 = __builtin_amdgcn_mfma_f32_16x16x32_bf16(a0, b0, acc0, 0, 0, 0);
            short8 a1 = *(const short8*)&sX1b[l16][k0 + 32 + quad * 8];
            short8 b1 = *(const short8*)(hrow + k0 + 32);
            acc1 = __builtin_amdgcn_mfma_f32_16x16x32_bf16(a1, b1, acc1, 0, 0, 0);
        }
        #pragma unroll
        for (int i = 0; i < 4; i++)
            sLogP[quad * 4 + i][w * 16 + l16] = acc0[i] + acc1[i];  // D: row=quad*4+i, col=l16
    }
    __syncthreads();

    // ---------- Phase C: softmax + margin candidate mask (wave w owns tokens 2w, 2w+1) ----------
    unsigned long long candA, candB;
    {
        float lA = sLogP[2 * w][lane];
        float lB = sLogP[2 * w + 1][lane];
        float mA = lA, mB = lB;
        #pragma unroll
        for (int k = 1; k < 64; k <<= 1) {              // interleaved chains for ILP
            mA = fmaxf(mA, __shfl_xor(mA, k));
            mB = fmaxf(mB, __shfl_xor(mB, k));
        }
        float eA = __expf(lA - mA), eB = __expf(lB - mB);
        float sA = eA, sB = eB;
        #pragma unroll
        for (int k = 1; k < 64; k <<= 1) {
            sA += __shfl_xor(sA, k);
            sB += __shfl_xor(sB, k);
        }
        sP[2 * w][lane]     = __float2bfloat16(eA / sA);
        sP[2 * w + 1][lane] = __float2bfloat16(eB / sB);
        // True argmax has approx logit >= mx - 2*eps; Delta=2.5 ~ 15 sigma of
        // the bf16 logit error -- strictly safer coverage than top-4.
        candA = __ballot(lA >= mA - CAND_DELTA);
        candB = __ballot(lB >= mB - CAND_DELTA);
    }

    // ---------- Phase C'': exact fp32 logits for candidates; argmax (half-wave per token) ----------
    {
        unsigned long long cm = ((lane >> 5) & 1) ? candB : candA;
        float bv = -3.4e38f; int bi = 0;
        while (cm) {                                    // ascending v -> ties keep lowest idx
            int v = __ffsll(cm) - 1;
            cm &= cm - 1;
            const float4* hr = (const float4*)(headF + (long)v * DIMS);
            float p = 0.f;
            #pragma unroll
            for (int c = 0; c < 8; c++) {
                float4 hv = hr[l32 + c * 32];
                p = fmaf(xv[c].x, hv.x, p); p = fmaf(xv[c].y, hv.y, p);
                p = fmaf(xv[c].z, hv.z, p); p = fmaf(xv[c].w, hv.w, p);
            }
            p += __shfl_xor(p, 1); p += __shfl_xor(p, 2);
            p += __shfl_xor(p, 4); p += __shfl_xor(p, 8);
            p += __shfl_xor(p, 16);                     // reduce within 32-lane half
            if (p > bv) { bv = p; bi = v; }
        }
        if (l32 == 0) out[IDX_OFF + tok] = (float)bi;   // np.argmax ties -> lowest index
    }
    __syncthreads();   // sP writes (C) visible before D reads

    // ---------- Phase D: soft_emb = P.emb via bf16 MFMA + blend + fp32 store (R4-proven) ----------
    #pragma unroll 1
    for (int i = 0; i < 8; i++) {
        int n0 = (i * 8 + w) * 16;                    // 64 wave-disjoint n-tiles
        f32x4 acc = {0.f, 0.f, 0.f, 0.f};
        #pragma unroll
        for (int k0 = 0; k0 < VOCAB; k0 += 32) {
            short8 a = *(const short8*)&sP[l16][k0 + quad * 8];
            short8 b = *(const short8*)(embT + (long)(n0 + l16) * VOCAB + k0 + quad * 8);
            acc = __builtin_amdgcn_mfma_f32_16x16x32_bf16(a, b, acc, 0, 0, 0);
        }
        #pragma unroll
        for (int r = 0; r < 4; r++) {
            int m = quad * 4 + r;                     // D: row=quad*4+r (token), col=l16 (dim)
            int n = n0 + l16;
            float sg = sSg[m];
            float x1f = bf2f(*(const unsigned short*)&sX1b[m][n]);
            out[(t0 + m) * (long)DIMS + n] = x1f * (1.f - sg) + acc[r] * sg;
        }
    }
}

extern "C" void kernel_launch(void* const* d_in, const int* in_sizes, int n_in,
                              void* d_out, int out_size, void* d_ws, size_t ws_size,
                              hipStream_t stream) {
    const float* xp    = (const float*)d_in[0];
    const int*   idxp  = (const int*)d_in[1];
    const float* embp  = (const float*)d_in[2];
    const float* headp = (const float*)d_in[3];
    const float* gp    = (const float*)d_in[4];
    const float* sgp   = (const float*)d_in[5];
    float*       outp  = (float*)d_out;

    __hip_bfloat16* headB = (__hip_bfloat16*)d_ws;                        // 128 KB
    __hip_bfloat16* embT  = (__hip_bfloat16*)((char*)d_ws + 131072);      // 128 KB

    prep_weights<<<dim3(256), dim3(256), 0, stream>>>(headp, embp, headB, embT);
    fused_block<<<dim3(NTOK / TTILE), dim3(TPB), 0, stream>>>(
        xp, idxp, embp, gp, sgp, headp, headB, embT, outp);
}